// Round 4
// baseline (897.019 us; speedup 1.0000x reference)
//
#include <hip/hip_runtime.h>
#include <math.h>

#define B_ 8
#define H_ 128
#define L_ 16384
#define N_ 16
#define CHUNK_ 64
#define NCH_ 256   // L_ / CHUNK_

typedef float f32x4 __attribute__((ext_vector_type(4)));
typedef short bf16x8 __attribute__((ext_vector_type(8)));

static __device__ __forceinline__ unsigned int f2bf(float f) {
  unsigned int u = __float_as_uint(f);
  return (u + 0x7FFFu + ((u >> 16) & 1u)) >> 16;   // RNE bf16
}
static __device__ __forceinline__ float bf2f(unsigned int us) {
  return __uint_as_float(us << 16);
}

// ---------------------------------------------------------------------------
// prep2: parallel weight bf16 conversion + SSM constants + FiLM
// ---------------------------------------------------------------------------
__global__ __launch_bounds__(256) void prep2_kernel(
    const float* __restrict__ lin_w, const float* __restrict__ out_w,
    const float* __restrict__ log_dt, const float* __restrict__ log_A_real,
    const float* __restrict__ A_imag, const float* __restrict__ C_re,
    const float* __restrict__ C_im, const float* __restrict__ cond,
    const float* __restrict__ film_w, const float* __restrict__ film_b,
    unsigned short* __restrict__ wA16, unsigned short* __restrict__ wB16,
    float* __restrict__ consts,
    float* __restrict__ gact, float* __restrict__ bact)
{
  int blk = blockIdx.x, t = threadIdx.x;
  if (blk < 16) {
    int base = blk * 1024;
    #pragma unroll
    for (int it = 0; it < 4; it++) {
      int i = base + it * 256 + t;
      wA16[i] = (unsigned short)f2bf(lin_w[i]);
      wB16[i] = (unsigned short)f2bf(out_w[i]);
    }
  } else if (blk == 16) {
    for (int i = t; i < H_ * N_; i += 256) {
      int h = i >> 4, n = i & 15;
      float dt  = expf(log_dt[h]);
      float Are = -expf(log_A_real[i]);
      float Aim = A_imag[i];
      float dre = dt * Are, dim = dt * Aim;
      float er  = expf(dre);
      float wre = er * cosf(dim);
      float wim = er * sinf(dim);
      float den = Are * Are + Aim * Aim;
      float nre = wre - 1.0f, nim = wim;
      float dBre = (nre * Are + nim * Aim) / den;
      float dBim = (nim * Are - nre * Aim) / den;
      float cr = C_re[i], ci = C_im[i];
      float cere = cr * dBre - ci * dBim;
      float ceim = cr * dBim + ci * dBre;
      float e2   = expf((float)CHUNK_ * dre);
      float wcre = e2 * cosf((float)CHUNK_ * dim);
      float wcim = e2 * sinf((float)CHUNK_ * dim);
      float* cb = consts + h * 96;
      cb[n]      = wre;  cb[16 + n] = wim;
      cb[32 + n] = cere; cb[48 + n] = ceim;
      cb[64 + n] = wcre; cb[80 + n] = wcim;
    }
  } else {
    for (int i = t; i < B_ * 2 * H_; i += 256) {
      int b = i >> 8, k = i & 255;
      float acc = film_b[k];
      #pragma unroll
      for (int c = 0; c < 4; c++) acc += cond[b * 4 + c] * film_w[k * 4 + c];
      if (k < H_) gact[b * H_ + k] = acc;
      else        bact[b * H_ + (k - H_)] = acc;
    }
  }
}

// ---------------------------------------------------------------------------
// MFMA GEMM, 128g x 64j tile, K=128.  MODE 0: x f32 -> u bf16 (+prelu).
// MODE 1: y bf16 -> z bf16 (+bias).  bf16 intermediates live in the first
// 32KB of each row's 64KB f32 slot in d_out: ushort idx = row*32768 + j.
// Col-disjoint across blocks -> in-place safe.
// ---------------------------------------------------------------------------
template<int MODE>
__global__ __launch_bounds__(256) void mgemm_kernel(
    const void* inv, const unsigned short* __restrict__ w16,
    const float* __restrict__ bias, const float* __restrict__ prelu_a,
    unsigned short* __restrict__ outb)
{
  __shared__ __align__(16) unsigned short xT[64 * 128];  // swizzled [j][h] bf16
  char* xb = (char*)xT;
  int tid = threadIdx.x;
  int blk = blockIdx.x;
  int b   = blk >> 8;
  int jb  = (blk & 255) << 6;

  // ---- stage x^T tile (64j x 128h) as bf16, XOR-swizzled ----
  {
    int hp = tid >> 4;        // h-group: h0 = hp*8
    int jq = tid & 15;        // j-group: j  = jq*4 + jj
    int h0 = hp << 3;
    if (MODE == 0) {
      const float* inb = (const float*)inv + ((size_t)b * H_) * L_ + jb;
      f32x4 r[8];
      #pragma unroll
      for (int rr = 0; rr < 8; rr++)
        r[rr] = *reinterpret_cast<const f32x4*>(&inb[(size_t)(h0 + rr) * L_ + (jq << 2)]);
      #pragma unroll
      for (int jj = 0; jj < 4; jj++) {
        int j = (jq << 2) + jj;
        uint4 pk;
        pk.x = f2bf(r[0][jj]) | (f2bf(r[1][jj]) << 16);
        pk.y = f2bf(r[2][jj]) | (f2bf(r[3][jj]) << 16);
        pk.z = f2bf(r[4][jj]) | (f2bf(r[5][jj]) << 16);
        pk.w = f2bf(r[6][jj]) | (f2bf(r[7][jj]) << 16);
        int addr = j * 256 + ((hp << 4) ^ ((j & 15) << 4));
        *reinterpret_cast<uint4*>(xb + addr) = pk;
      }
    } else {
      const unsigned short* ub = (const unsigned short*)inv;
      uint2 rv[8];
      #pragma unroll
      for (int rr = 0; rr < 8; rr++)
        rv[rr] = *reinterpret_cast<const uint2*>(
            ub + ((size_t)(b * H_ + h0 + rr)) * 32768 + jb + (jq << 2));
      #pragma unroll
      for (int jj = 0; jj < 4; jj++) {
        int j = (jq << 2) + jj;
        uint4 pk;
        #define EXT_(v) ((((jj & 2) ? (v).y : (v).x) >> ((jj & 1) << 4)) & 0xFFFFu)
        pk.x = EXT_(rv[0]) | (EXT_(rv[1]) << 16);
        pk.y = EXT_(rv[2]) | (EXT_(rv[3]) << 16);
        pk.z = EXT_(rv[4]) | (EXT_(rv[5]) << 16);
        pk.w = EXT_(rv[6]) | (EXT_(rv[7]) << 16);
        #undef EXT_
        int addr = j * 256 + ((hp << 4) ^ ((j & 15) << 4));
        *reinterpret_cast<uint4*>(xb + addr) = pk;
      }
    }
  }
  __syncthreads();

  // ---- MFMA compute: wave tile 64g x 32j ----
  int lane = tid & 63;
  int w    = tid >> 6;
  int wg   = w >> 1;
  int wj   = w & 1;
  int ln   = lane & 15;
  int q    = lane >> 4;
  f32x4 acc[4][2];
  #pragma unroll
  for (int mi = 0; mi < 4; mi++)
    #pragma unroll
    for (int n = 0; n < 2; n++) acc[mi][n] = (f32x4)0.0f;

  #pragma unroll
  for (int kb = 0; kb < 4; kb++) {
    bf16x8 a[4], bv[2];
    #pragma unroll
    for (int mi = 0; mi < 4; mi++)
      a[mi] = *reinterpret_cast<const bf16x8*>(
          &w16[(size_t)(wg * 64 + mi * 16 + ln) * 128 + kb * 32 + q * 8]);
    #pragma unroll
    for (int n = 0; n < 2; n++) {
      int jl = wj * 32 + n * 16 + ln;
      int ar = jl * 256 + (((kb << 6) + (q << 4)) ^ ((jl & 15) << 4));
      bv[n] = *reinterpret_cast<bf16x8*>(xb + ar);
    }
    #pragma unroll
    for (int mi = 0; mi < 4; mi++)
      #pragma unroll
      for (int n = 0; n < 2; n++)
        acc[mi][n] = __builtin_amdgcn_mfma_f32_16x16x32_bf16(a[mi], bv[n], acc[mi][n], 0, 0, 0);
  }

  // ---- epilogue: bf16 stores into row slots ----
  float pa = (MODE == 0) ? prelu_a[0] : 0.0f;
  #pragma unroll
  for (int mi = 0; mi < 4; mi++) {
    #pragma unroll
    for (int r = 0; r < 4; r++) {
      int g = wg * 64 + mi * 16 + q * 4 + r;
      float bvs = bias[g];
      float v0 = acc[mi][0][r] + bvs;
      float v1 = acc[mi][1][r] + bvs;
      if (MODE == 0) {
        v0 = (v0 > 0.0f) ? v0 : pa * v0;
        v1 = (v1 > 0.0f) ? v1 : pa * v1;
      }
      size_t ob = ((size_t)(b * H_ + g)) * 32768 + jb + wj * 32 + ln;
      outb[ob]      = (unsigned short)f2bf(v0);
      outb[ob + 16] = (unsigned short)f2bf(v1);
    }
  }
}

// ---------------------------------------------------------------------------
// scan2: LDS-staged chunked SSM scan, bf16 row in/out, in-place per row.
// 512 thr: all stage; threads 0..255 scan (chunk = 64 elems).  Cross-chunk
// combine = 8-step Kogge-Stone over chunk states in LDS.
// LDS row swizzle (uint granularity): phys u = u ^ ((u>>5)&31).
// ---------------------------------------------------------------------------
__global__ __launch_bounds__(512, 4) void scan2_kernel(
    unsigned short* ub, const float* __restrict__ consts, const float* __restrict__ Dp)
{
  __shared__ unsigned int rowl[8192];      // 16384 bf16, swizzled
  __shared__ float st[NCH_ * 34];          // chunk states [c][2n], pad 34
  int tid = threadIdx.x;
  int row = blockIdx.x;
  int h   = row & 127;
  const float* cb = consts + h * 96;
  unsigned int* grow = (unsigned int*)ub + (size_t)row * 16384;  // first 8192 uints = bf16 row

  // ---- stage in (coalesced uint4, swizzled b128 LDS stores) ----
  #pragma unroll
  for (int rd = 0; rd < 4; rd++) {
    int u0  = rd * 2048 + tid * 4;
    uint4 v = *reinterpret_cast<const uint4*>(grow + u0);
    int x   = (u0 >> 5) & 31;
    int bse = u0 ^ (x & ~3);
    int pl  = x & 3;
    if (pl & 1) v = make_uint4(v.y, v.x, v.w, v.z);
    if (pl & 2) v = make_uint4(v.z, v.w, v.x, v.y);
    *reinterpret_cast<uint4*>(&rowl[bse]) = v;
  }
  __syncthreads();

  int c = tid;                 // chunk id (active if < NCH_)
  float wre[16], wim[16];
  #pragma unroll
  for (int n = 0; n < 16; n++) { wre[n] = cb[n]; wim[n] = cb[16 + n]; }

  float sre[16], sim[16];
  #pragma unroll
  for (int n = 0; n < 16; n++) { sre[n] = 0.0f; sim[n] = 0.0f; }

  // ---- phase 1: local chunk states ----
  if (c < NCH_) {
    for (int e2 = 0; e2 < 32; e2++) {
      unsigned int pv = rowl[(c * 32 + e2) ^ (c & 31)];
      float u0 = bf2f(pv & 0xFFFFu), u1 = bf2f(pv >> 16);
      #pragma unroll
      for (int n = 0; n < 16; n++) {
        float nr = fmaf(wre[n], sre[n], fmaf(-wim[n], sim[n], u0));
        float ni = fmaf(wre[n], sim[n], wim[n] * sre[n]);
        sre[n] = nr; sim[n] = ni;
      }
      #pragma unroll
      for (int n = 0; n < 16; n++) {
        float nr = fmaf(wre[n], sre[n], fmaf(-wim[n], sim[n], u1));
        float ni = fmaf(wre[n], sim[n], wim[n] * sre[n]);
        sre[n] = nr; sim[n] = ni;
      }
    }
    #pragma unroll
    for (int n = 0; n < 16; n++) {
      st[c * 34 + 2 * n]     = sre[n];
      st[c * 34 + 2 * n + 1] = sim[n];
    }
  }
  __syncthreads();

  // ---- Kogge-Stone inclusive prefix over chunks: b[c] += wc^(2^k)*b[c-2^k] ----
  float mre[16], mim[16];
  #pragma unroll
  for (int n = 0; n < 16; n++) { mre[n] = cb[64 + n]; mim[n] = cb[80 + n]; }
  #pragma unroll
  for (int k = 0; k < 8; k++) {
    int off = 1 << k;
    float pr[16], pi[16];
    bool act = (c < NCH_) && (c >= off);
    if (act) {
      #pragma unroll
      for (int n = 0; n < 16; n++) {
        pr[n] = st[(c - off) * 34 + 2 * n];
        pi[n] = st[(c - off) * 34 + 2 * n + 1];
      }
    }
    __syncthreads();
    if (act) {
      #pragma unroll
      for (int n = 0; n < 16; n++) {
        sre[n] = fmaf(mre[n], pr[n], fmaf(-mim[n], pi[n], sre[n]));
        sim[n] = fmaf(mre[n], pi[n], fmaf( mim[n], pr[n], sim[n]));
      }
      #pragma unroll
      for (int n = 0; n < 16; n++) {
        st[c * 34 + 2 * n]     = sre[n];
        st[c * 34 + 2 * n + 1] = sim[n];
      }
    }
    #pragma unroll
    for (int n = 0; n < 16; n++) {
      float r = mre[n], i = mim[n];
      mre[n] = r * r - i * i;
      mim[n] = 2.0f * r * i;
    }
    __syncthreads();
  }

  // ---- phase 2: seeded re-scan, emit y (bf16) into LDS row ----
  float cre[16], cim[16];
  #pragma unroll
  for (int n = 0; n < 16; n++) { cre[n] = cb[32 + n]; cim[n] = cb[48 + n]; }
  float Dv = Dp[h];
  if (c < NCH_) {
    if (c == 0) {
      #pragma unroll
      for (int n = 0; n < 16; n++) { sre[n] = 0.0f; sim[n] = 0.0f; }
    } else {
      #pragma unroll
      for (int n = 0; n < 16; n++) {
        sre[n] = st[(c - 1) * 34 + 2 * n];
        sim[n] = st[(c - 1) * 34 + 2 * n + 1];
      }
    }
    for (int e2 = 0; e2 < 32; e2++) {
      int pu = (c * 32 + e2) ^ (c & 31);
      unsigned int pv = rowl[pu];
      float u0 = bf2f(pv & 0xFFFFu), u1 = bf2f(pv >> 16);
      float y0 = 0.0f, y1 = 0.0f;
      #pragma unroll
      for (int n = 0; n < 16; n++) {
        float nr = fmaf(wre[n], sre[n], fmaf(-wim[n], sim[n], u0));
        float ni = fmaf(wre[n], sim[n], wim[n] * sre[n]);
        sre[n] = nr; sim[n] = ni;
        y0 = fmaf(cre[n], nr, fmaf(-cim[n], ni, y0));
      }
      #pragma unroll
      for (int n = 0; n < 16; n++) {
        float nr = fmaf(wre[n], sre[n], fmaf(-wim[n], sim[n], u1));
        float ni = fmaf(wre[n], sim[n], wim[n] * sre[n]);
        sre[n] = nr; sim[n] = ni;
        y1 = fmaf(cre[n], nr, fmaf(-cim[n], ni, y1));
      }
      y0 = fmaf(Dv, u0, 2.0f * y0);
      y1 = fmaf(Dv, u1, 2.0f * y1);
      rowl[pu] = f2bf(y0) | (f2bf(y1) << 16);
    }
  }
  __syncthreads();

  // ---- stage out (swizzled b128 LDS reads, coalesced uint4 stores) ----
  #pragma unroll
  for (int rd = 0; rd < 4; rd++) {
    int u0  = rd * 2048 + tid * 4;
    int x   = (u0 >> 5) & 31;
    int bse = u0 ^ (x & ~3);
    int pl  = x & 3;
    uint4 v = *reinterpret_cast<const uint4*>(&rowl[bse]);
    if (pl & 1) v = make_uint4(v.y, v.x, v.w, v.z);
    if (pl & 2) v = make_uint4(v.z, v.w, v.x, v.y);
    *reinterpret_cast<uint4*>(grow + u0) = v;
  }
}

// ---------------------------------------------------------------------------
// stats1: per-row (b,g) sums of z (bf16) -> ws partials
// ---------------------------------------------------------------------------
__global__ __launch_bounds__(256) void stats1_kernel(
    const unsigned short* __restrict__ ub,
    float* __restrict__ sums, float* __restrict__ sumsq)
{
  int row = blockIdx.x, tid = threadIdx.x;
  const unsigned int* zr = (const unsigned int*)ub + (size_t)row * 16384;
  float s1 = 0.0f, s2 = 0.0f;
  #pragma unroll
  for (int rd = 0; rd < 8; rd++) {
    uint4 v = *reinterpret_cast<const uint4*>(zr + rd * 1024 + tid * 4);
    unsigned int ws_[4] = {v.x, v.y, v.z, v.w};
    #pragma unroll
    for (int k = 0; k < 4; k++) {
      float f0 = bf2f(ws_[k] & 0xFFFFu), f1 = bf2f(ws_[k] >> 16);
      s1 += f0 + f1;
      s2 = fmaf(f0, f0, fmaf(f1, f1, s2));
    }
  }
  #pragma unroll
  for (int off = 1; off < 64; off <<= 1) {
    s1 += __shfl_xor(s1, off);
    s2 += __shfl_xor(s2, off);
  }
  __shared__ float a1[4], a2[4];
  int wv = tid >> 6;
  if ((tid & 63) == 0) { a1[wv] = s1; a2[wv] = s2; }
  __syncthreads();
  if (tid == 0) {
    sums[row]  = a1[0] + a1[1] + a1[2] + a1[3];
    sumsq[row] = a2[0] + a2[1] + a2[2] + a2[3];
  }
}

__global__ void stats2_kernel(const float* __restrict__ sums,
                              const float* __restrict__ sumsq,
                              float* __restrict__ meanp, float* __restrict__ invp)
{
  int g = threadIdx.x;
  if (g < H_) {
    double s1 = 0.0, s2 = 0.0;
    #pragma unroll
    for (int b = 0; b < B_; b++) {
      s1 += (double)sums[b * H_ + g];
      s2 += (double)sumsq[b * H_ + g];
    }
    double cnt = (double)B_ * (double)L_;
    double mu  = s1 / cnt;
    double var = s2 / cnt - mu * mu;
    meanp[g] = (float)mu;
    invp[g]  = (float)(1.0 / sqrt(var + 1e-5));
  }
}

// ---------------------------------------------------------------------------
// final2: one block per row; z bf16 -> regs, barrier, BN+FiLM+prelu+residual,
// write f32 over the same row slot (in-place safe via the barrier).
// ---------------------------------------------------------------------------
__global__ __launch_bounds__(256) void final2_kernel(
    unsigned short* __restrict__ ub, float* __restrict__ outf,
    const float* __restrict__ x,
    const float* __restrict__ meanp, const float* __restrict__ invp,
    const float* __restrict__ gact, const float* __restrict__ bact,
    const float* __restrict__ prelu2_a, const float* __restrict__ res_w)
{
  int row = blockIdx.x, tid = threadIdx.x;
  int b = row >> 7, g = row & 127;
  const unsigned int* zr = (const unsigned int*)ub + (size_t)row * 16384;
  uint4 zq0 = *reinterpret_cast<const uint4*>(zr + 0 * 1024 + tid * 4);
  uint4 zq1 = *reinterpret_cast<const uint4*>(zr + 1 * 1024 + tid * 4);
  uint4 zq2 = *reinterpret_cast<const uint4*>(zr + 2 * 1024 + tid * 4);
  uint4 zq3 = *reinterpret_cast<const uint4*>(zr + 3 * 1024 + tid * 4);
  uint4 zq4 = *reinterpret_cast<const uint4*>(zr + 4 * 1024 + tid * 4);
  uint4 zq5 = *reinterpret_cast<const uint4*>(zr + 5 * 1024 + tid * 4);
  uint4 zq6 = *reinterpret_cast<const uint4*>(zr + 6 * 1024 + tid * 4);
  uint4 zq7 = *reinterpret_cast<const uint4*>(zr + 7 * 1024 + tid * 4);
  __syncthreads();   // all z reads complete before any f32 write to the slot

  float m  = meanp[g], iv = invp[g];
  float ga = gact[b * H_ + g], bb = bact[b * H_ + g];
  float rw = res_w[g], pa = prelu2_a[0];
  const float* xr = x + (size_t)row * L_;
  float* orow = outf + (size_t)row * L_;

  uint4 zqa[8] = {zq0, zq1, zq2, zq3, zq4, zq5, zq6, zq7};
  #pragma unroll
  for (int rd = 0; rd < 8; rd++) {
    int e0 = rd * 2048 + tid * 8;
    f32x4 x0 = *reinterpret_cast<const f32x4*>(xr + e0);
    f32x4 x1 = *reinterpret_cast<const f32x4*>(xr + e0 + 4);
    unsigned int wz[4] = {zqa[rd].x, zqa[rd].y, zqa[rd].z, zqa[rd].w};
    f32x4 o0, o1;
    #pragma unroll
    for (int k = 0; k < 4; k++) {
      float z0 = bf2f(wz[k] & 0xFFFFu), z1 = bf2f(wz[k] >> 16);
      float v0 = fmaf((z0 - m) * iv, ga, bb);
      float v1 = fmaf((z1 - m) * iv, ga, bb);
      v0 = (v0 > 0.0f) ? v0 : pa * v0;
      v1 = (v1 > 0.0f) ? v1 : pa * v1;
      float xa = (k < 2) ? x0[2 * k] : x1[2 * k - 4];
      float xbv = (k < 2) ? x0[2 * k + 1] : x1[2 * k - 3];
      float r0 = fmaf(rw, xa, v0);
      float r1 = fmaf(rw, xbv, v1);
      if (k < 2) { o0[2 * k] = r0; o0[2 * k + 1] = r1; }
      else       { o1[2 * k - 4] = r0; o1[2 * k - 3] = r1; }
    }
    *reinterpret_cast<f32x4*>(orow + e0)     = o0;
    *reinterpret_cast<f32x4*>(orow + e0 + 4) = o1;
  }
}

// ---------------------------------------------------------------------------
extern "C" void kernel_launch(void* const* d_in, const int* in_sizes, int n_in,
                              void* d_out, int out_size, void* d_ws, size_t ws_size,
                              hipStream_t stream)
{
  const float* x        = (const float*)d_in[0];
  const float* cond     = (const float*)d_in[1];
  const float* lin_w    = (const float*)d_in[2];
  const float* lin_b    = (const float*)d_in[3];
  const float* prelu1_a = (const float*)d_in[4];
  const float* log_dt   = (const float*)d_in[5];
  const float* log_A    = (const float*)d_in[6];
  const float* A_imag   = (const float*)d_in[7];
  const float* C_re     = (const float*)d_in[8];
  const float* C_im     = (const float*)d_in[9];
  const float* Dp       = (const float*)d_in[10];
  const float* out_w    = (const float*)d_in[11];
  const float* out_b    = (const float*)d_in[12];
  const float* film_w   = (const float*)d_in[13];
  const float* film_b   = (const float*)d_in[14];
  const float* prelu2_a = (const float*)d_in[15];
  const float* res_w    = (const float*)d_in[16];
  float* outf = (float*)d_out;
  unsigned short* ubuf = (unsigned short*)d_out;

  char* wsb = (char*)d_ws;               // ~129 KB total
  float* consts         = (float*)(wsb + 0);        // 12288 f32 = 48 KB
  unsigned short* wA16  = (unsigned short*)(wsb + 49152);   // 32 KB
  unsigned short* wB16  = (unsigned short*)(wsb + 81920);   // 32 KB
  float* gact           = (float*)(wsb + 114688);   // 4 KB
  float* bact           = (float*)(wsb + 118784);   // 4 KB
  float* meanp          = (float*)(wsb + 122880);   // 512 B
  float* invp           = (float*)(wsb + 123392);   // 512 B
  float* sums           = (float*)(wsb + 123904);   // 4 KB
  float* sumsq          = (float*)(wsb + 128000);   // 4 KB

  prep2_kernel<<<18, 256, 0, stream>>>(lin_w, out_w, log_dt, log_A, A_imag, C_re, C_im,
                                       cond, film_w, film_b, wA16, wB16, consts, gact, bact);
  // lin + prelu: x (f32) -> u (bf16 row slots in d_out)
  mgemm_kernel<0><<<2048, 256, 0, stream>>>(x, wA16, lin_b, prelu1_a, ubuf);
  // SSM scan: u -> y, bf16, in place per row
  scan2_kernel<<<1024, 512, 0, stream>>>(ubuf, consts, Dp);
  // out layer + bias: y (bf16) -> z (bf16), in place
  mgemm_kernel<1><<<2048, 256, 0, stream>>>(ubuf, wB16, out_b, nullptr, ubuf);
  // BN stats over z
  stats1_kernel<<<1024, 256, 0, stream>>>(ubuf, sums, sumsq);
  stats2_kernel<<<1, 128, 0, stream>>>(sums, sumsq, meanp, invp);
  // BN + FiLM + prelu2 + residual: z (bf16) -> out (f32), in place per row
  final2_kernel<<<1024, 256, 0, stream>>>(ubuf, outf, x, meanp, invp, gact, bact,
                                          prelu2_a, res_w);
}

// Round 5
// 331.817 us; speedup vs baseline: 2.7034x; 2.7034x over previous
//
#include <hip/hip_runtime.h>
#include <math.h>

#define B_ 8
#define H_ 128
#define L_ 16384
#define N_ 16
#define CHUNK_ 64
#define NCH_ 256   // L_ / CHUNK_

typedef float f32x4 __attribute__((ext_vector_type(4)));
typedef short bf16x8 __attribute__((ext_vector_type(8)));

static __device__ __forceinline__ unsigned int f2bf(float f) {
  unsigned int u = __float_as_uint(f);
  return (u + 0x7FFFu + ((u >> 16) & 1u)) >> 16;   // RNE bf16
}
static __device__ __forceinline__ float bf2f(unsigned int us) {
  return __uint_as_float(us << 16);
}

// ---------------------------------------------------------------------------
// prep2: parallel weight bf16 conversion + SSM constants + FiLM
// ---------------------------------------------------------------------------
__global__ __launch_bounds__(256) void prep2_kernel(
    const float* __restrict__ lin_w, const float* __restrict__ out_w,
    const float* __restrict__ log_dt, const float* __restrict__ log_A_real,
    const float* __restrict__ A_imag, const float* __restrict__ C_re,
    const float* __restrict__ C_im, const float* __restrict__ cond,
    const float* __restrict__ film_w, const float* __restrict__ film_b,
    unsigned short* __restrict__ wA16, unsigned short* __restrict__ wB16,
    float* __restrict__ consts,
    float* __restrict__ gact, float* __restrict__ bact)
{
  int blk = blockIdx.x, t = threadIdx.x;
  if (blk < 16) {
    int base = blk * 1024;
    #pragma unroll
    for (int it = 0; it < 4; it++) {
      int i = base + it * 256 + t;
      wA16[i] = (unsigned short)f2bf(lin_w[i]);
      wB16[i] = (unsigned short)f2bf(out_w[i]);
    }
  } else if (blk == 16) {
    for (int i = t; i < H_ * N_; i += 256) {
      int h = i >> 4, n = i & 15;
      float dt  = expf(log_dt[h]);
      float Are = -expf(log_A_real[i]);
      float Aim = A_imag[i];
      float dre = dt * Are, dim = dt * Aim;
      float er  = expf(dre);
      float wre = er * cosf(dim);
      float wim = er * sinf(dim);
      float den = Are * Are + Aim * Aim;
      float nre = wre - 1.0f, nim = wim;
      float dBre = (nre * Are + nim * Aim) / den;
      float dBim = (nim * Are - nre * Aim) / den;
      float cr = C_re[i], ci = C_im[i];
      float cere = cr * dBre - ci * dBim;
      float ceim = cr * dBim + ci * dBre;
      float e2   = expf((float)CHUNK_ * dre);
      float wcre = e2 * cosf((float)CHUNK_ * dim);
      float wcim = e2 * sinf((float)CHUNK_ * dim);
      float* cb = consts + h * 96;
      cb[n]      = wre;  cb[16 + n] = wim;
      cb[32 + n] = cere; cb[48 + n] = ceim;
      cb[64 + n] = wcre; cb[80 + n] = wcim;
    }
  } else {
    for (int i = t; i < B_ * 2 * H_; i += 256) {
      int b = i >> 8, k = i & 255;
      float acc = film_b[k];
      #pragma unroll
      for (int c = 0; c < 4; c++) acc += cond[b * 4 + c] * film_w[k * 4 + c];
      if (k < H_) gact[b * H_ + k] = acc;
      else        bact[b * H_ + (k - H_)] = acc;
    }
  }
}

// ---------------------------------------------------------------------------
// MFMA GEMM, 128g x 64j tile, K=128.  MODE 0: x f32 -> u bf16 (+prelu).
// MODE 1: y bf16 -> z bf16 (+bias).  bf16 intermediates live in the first
// 32KB of each row's 64KB f32 slot in d_out: ushort idx = row*32768 + j.
// Col-disjoint across blocks -> in-place safe.
// ---------------------------------------------------------------------------
template<int MODE>
__global__ __launch_bounds__(256) void mgemm_kernel(
    const void* inv, const unsigned short* __restrict__ w16,
    const float* __restrict__ bias, const float* __restrict__ prelu_a,
    unsigned short* __restrict__ outb)
{
  __shared__ __align__(16) unsigned short xT[64 * 128];  // swizzled [j][h] bf16
  char* xb = (char*)xT;
  int tid = threadIdx.x;
  int blk = blockIdx.x;
  int b   = blk >> 8;
  int jb  = (blk & 255) << 6;

  // ---- stage x^T tile (64j x 128h) as bf16, XOR-swizzled ----
  {
    int hp = tid >> 4;        // h-group: h0 = hp*8
    int jq = tid & 15;        // j-group: j  = jq*4 + jj
    int h0 = hp << 3;
    if (MODE == 0) {
      const float* inb = (const float*)inv + ((size_t)b * H_) * L_ + jb;
      f32x4 r[8];
      #pragma unroll
      for (int rr = 0; rr < 8; rr++)
        r[rr] = *reinterpret_cast<const f32x4*>(&inb[(size_t)(h0 + rr) * L_ + (jq << 2)]);
      #pragma unroll
      for (int jj = 0; jj < 4; jj++) {
        int j = (jq << 2) + jj;
        uint4 pk;
        pk.x = f2bf(r[0][jj]) | (f2bf(r[1][jj]) << 16);
        pk.y = f2bf(r[2][jj]) | (f2bf(r[3][jj]) << 16);
        pk.z = f2bf(r[4][jj]) | (f2bf(r[5][jj]) << 16);
        pk.w = f2bf(r[6][jj]) | (f2bf(r[7][jj]) << 16);
        int addr = j * 256 + ((hp << 4) ^ ((j & 15) << 4));
        *reinterpret_cast<uint4*>(xb + addr) = pk;
      }
    } else {
      const unsigned short* ub = (const unsigned short*)inv;
      uint2 rv[8];
      #pragma unroll
      for (int rr = 0; rr < 8; rr++)
        rv[rr] = *reinterpret_cast<const uint2*>(
            ub + ((size_t)(b * H_ + h0 + rr)) * 32768 + jb + (jq << 2));
      #pragma unroll
      for (int jj = 0; jj < 4; jj++) {
        int j = (jq << 2) + jj;
        uint4 pk;
        #define EXT_(v) ((((jj & 2) ? (v).y : (v).x) >> ((jj & 1) << 4)) & 0xFFFFu)
        pk.x = EXT_(rv[0]) | (EXT_(rv[1]) << 16);
        pk.y = EXT_(rv[2]) | (EXT_(rv[3]) << 16);
        pk.z = EXT_(rv[4]) | (EXT_(rv[5]) << 16);
        pk.w = EXT_(rv[6]) | (EXT_(rv[7]) << 16);
        #undef EXT_
        int addr = j * 256 + ((hp << 4) ^ ((j & 15) << 4));
        *reinterpret_cast<uint4*>(xb + addr) = pk;
      }
    }
  }
  __syncthreads();

  // ---- MFMA compute: wave tile 64g x 32j ----
  int lane = tid & 63;
  int w    = tid >> 6;
  int wg   = w >> 1;
  int wj   = w & 1;
  int ln   = lane & 15;
  int q    = lane >> 4;
  f32x4 acc[4][2];
  #pragma unroll
  for (int mi = 0; mi < 4; mi++)
    #pragma unroll
    for (int n = 0; n < 2; n++) acc[mi][n] = (f32x4)0.0f;

  #pragma unroll
  for (int kb = 0; kb < 4; kb++) {
    bf16x8 a[4], bv[2];
    #pragma unroll
    for (int mi = 0; mi < 4; mi++)
      a[mi] = *reinterpret_cast<const bf16x8*>(
          &w16[(size_t)(wg * 64 + mi * 16 + ln) * 128 + kb * 32 + q * 8]);
    #pragma unroll
    for (int n = 0; n < 2; n++) {
      int jl = wj * 32 + n * 16 + ln;
      int ar = jl * 256 + (((kb << 6) + (q << 4)) ^ ((jl & 15) << 4));
      bv[n] = *reinterpret_cast<bf16x8*>(xb + ar);
    }
    #pragma unroll
    for (int mi = 0; mi < 4; mi++)
      #pragma unroll
      for (int n = 0; n < 2; n++)
        acc[mi][n] = __builtin_amdgcn_mfma_f32_16x16x32_bf16(a[mi], bv[n], acc[mi][n], 0, 0, 0);
  }

  // ---- epilogue: bf16 stores into row slots ----
  float pa = (MODE == 0) ? prelu_a[0] : 0.0f;
  #pragma unroll
  for (int mi = 0; mi < 4; mi++) {
    #pragma unroll
    for (int r = 0; r < 4; r++) {
      int g = wg * 64 + mi * 16 + q * 4 + r;
      float bvs = bias[g];
      float v0 = acc[mi][0][r] + bvs;
      float v1 = acc[mi][1][r] + bvs;
      if (MODE == 0) {
        v0 = (v0 > 0.0f) ? v0 : pa * v0;
        v1 = (v1 > 0.0f) ? v1 : pa * v1;
      }
      size_t ob = ((size_t)(b * H_ + g)) * 32768 + jb + wj * 32 + ln;
      outb[ob]      = (unsigned short)f2bf(v0);
      outb[ob + 16] = (unsigned short)f2bf(v1);
    }
  }
}

// ---------------------------------------------------------------------------
// scan3: 4-way mode-split chunked SSM scan.  1024 thr; thread = (chunk c =
// tid>>2, mode-group m = tid&3, modes 4m..4m+3).  ~50 VGPR/thread -> no
// spill (round-4 683us regression was spill traffic: 3.3GB HBM).
// Row in LDS (bf16, XOR-swizzled); chunk states in LDS; Kogge-Stone combine;
// quad __shfl_xor reduction for y.  In-place per row.
// ---------------------------------------------------------------------------
__global__ __launch_bounds__(1024) void scan3_kernel(
    unsigned short* ub, const float* __restrict__ consts, const float* __restrict__ Dp)
{
  __shared__ unsigned int rowl[8192];      // 16384 bf16, swizzled
  __shared__ float st[NCH_ * 36];          // chunk states [c][m*8+2k(+1)], stride 36
  int tid = threadIdx.x;
  int row = blockIdx.x;
  int h   = row & 127;
  const float* cb = consts + h * 96;
  unsigned int* grow = (unsigned int*)ub + (size_t)row * 16384;

  // ---- stage in (coalesced uint4, swizzled LDS stores) ----
  #pragma unroll
  for (int rd = 0; rd < 2; rd++) {
    int u0  = rd * 4096 + tid * 4;
    uint4 v = *reinterpret_cast<const uint4*>(grow + u0);
    int x   = (u0 >> 5) & 31;
    int bse = u0 ^ (x & ~3);
    int pl  = x & 3;
    if (pl & 1) v = make_uint4(v.y, v.x, v.w, v.z);
    if (pl & 2) v = make_uint4(v.z, v.w, v.x, v.y);
    *reinterpret_cast<uint4*>(&rowl[bse]) = v;
  }
  __syncthreads();

  int c   = tid >> 2;          // chunk 0..255
  int m   = tid & 3;           // mode group
  int swz = c & 31;
  unsigned int* rc = rowl + c * 32;
  float* sc = st + c * 36 + m * 8;

  float wre[4], wim[4];
  #pragma unroll
  for (int k = 0; k < 4; k++) { wre[k] = cb[4*m+k]; wim[k] = cb[16+4*m+k]; }

  float sre[4] = {0.f,0.f,0.f,0.f}, sim[4] = {0.f,0.f,0.f,0.f};

  // ---- phase 1: local chunk states (4 modes/thread) ----
  for (int e = 0; e < 32; e++) {
    unsigned int pv = rc[e ^ swz];
    float u0 = bf2f(pv & 0xFFFFu), u1 = bf2f(pv >> 16);
    #pragma unroll
    for (int k = 0; k < 4; k++) {
      float nr = fmaf(wre[k], sre[k], fmaf(-wim[k], sim[k], u0));
      float ni = fmaf(wre[k], sim[k], wim[k] * sre[k]);
      sre[k] = nr; sim[k] = ni;
    }
    #pragma unroll
    for (int k = 0; k < 4; k++) {
      float nr = fmaf(wre[k], sre[k], fmaf(-wim[k], sim[k], u1));
      float ni = fmaf(wre[k], sim[k], wim[k] * sre[k]);
      sre[k] = nr; sim[k] = ni;
    }
  }
  #pragma unroll
  for (int k = 0; k < 4; k++) { sc[2*k] = sre[k]; sc[2*k+1] = sim[k]; }
  __syncthreads();

  // ---- Kogge-Stone inclusive prefix over chunks ----
  {
    float mre[4], mim[4];
    #pragma unroll
    for (int k = 0; k < 4; k++) { mre[k] = cb[64+4*m+k]; mim[k] = cb[80+4*m+k]; }
    for (int s = 0; s < 8; s++) {
      int off = 1 << s;
      float pr[4], pi[4];
      bool act = (c >= off);
      if (act) {
        const float* pc = st + (c - off) * 36 + m * 8;
        #pragma unroll
        for (int k = 0; k < 4; k++) { pr[k] = pc[2*k]; pi[k] = pc[2*k+1]; }
      }
      __syncthreads();
      if (act) {
        #pragma unroll
        for (int k = 0; k < 4; k++) {
          sre[k] = fmaf(mre[k], pr[k], fmaf(-mim[k], pi[k], sre[k]));
          sim[k] = fmaf(mre[k], pi[k], fmaf( mim[k], pr[k], sim[k]));
        }
        #pragma unroll
        for (int k = 0; k < 4; k++) { sc[2*k] = sre[k]; sc[2*k+1] = sim[k]; }
      }
      if (s < 7) {
        #pragma unroll
        for (int k = 0; k < 4; k++) {
          float r = mre[k], i2 = mim[k];
          mre[k] = r * r - i2 * i2;
          mim[k] = 2.0f * r * i2;
        }
      }
      __syncthreads();
    }
  }

  // ---- phase 2: seeded re-scan, emit y (quad-reduced) ----
  float cre[4], cim[4];
  #pragma unroll
  for (int k = 0; k < 4; k++) { cre[k] = cb[32+4*m+k]; cim[k] = cb[48+4*m+k]; }
  float Dv = Dp[h];
  if (c == 0) {
    #pragma unroll
    for (int k = 0; k < 4; k++) { sre[k] = 0.0f; sim[k] = 0.0f; }
  } else {
    const float* pc = st + (c - 1) * 36 + m * 8;
    #pragma unroll
    for (int k = 0; k < 4; k++) { sre[k] = pc[2*k]; sim[k] = pc[2*k+1]; }
  }
  for (int e = 0; e < 32; e++) {
    int p = e ^ swz;
    unsigned int pv = rc[p];
    float u0 = bf2f(pv & 0xFFFFu), u1 = bf2f(pv >> 16);
    float y0 = 0.0f, y1 = 0.0f;
    #pragma unroll
    for (int k = 0; k < 4; k++) {
      float nr = fmaf(wre[k], sre[k], fmaf(-wim[k], sim[k], u0));
      float ni = fmaf(wre[k], sim[k], wim[k] * sre[k]);
      sre[k] = nr; sim[k] = ni;
      y0 = fmaf(cre[k], nr, fmaf(-cim[k], ni, y0));
    }
    #pragma unroll
    for (int k = 0; k < 4; k++) {
      float nr = fmaf(wre[k], sre[k], fmaf(-wim[k], sim[k], u1));
      float ni = fmaf(wre[k], sim[k], wim[k] * sre[k]);
      sre[k] = nr; sim[k] = ni;
      y1 = fmaf(cre[k], nr, fmaf(-cim[k], ni, y1));
    }
    y0 += __shfl_xor(y0, 1); y0 += __shfl_xor(y0, 2);
    y1 += __shfl_xor(y1, 1); y1 += __shfl_xor(y1, 2);
    if (m == 0) {
      y0 = fmaf(Dv, u0, 2.0f * y0);
      y1 = fmaf(Dv, u1, 2.0f * y1);
      rc[p] = f2bf(y0) | (f2bf(y1) << 16);
    }
  }
  __syncthreads();

  // ---- stage out (swizzled LDS reads, coalesced uint4 stores) ----
  #pragma unroll
  for (int rd = 0; rd < 2; rd++) {
    int u0  = rd * 4096 + tid * 4;
    int x   = (u0 >> 5) & 31;
    int bse = u0 ^ (x & ~3);
    int pl  = x & 3;
    uint4 v = *reinterpret_cast<const uint4*>(&rowl[bse]);
    if (pl & 1) v = make_uint4(v.y, v.x, v.w, v.z);
    if (pl & 2) v = make_uint4(v.z, v.w, v.x, v.y);
    *reinterpret_cast<uint4*>(grow + u0) = v;
  }
}

// ---------------------------------------------------------------------------
// stats1: per-row (b,g) sums of z (bf16) -> ws partials
// ---------------------------------------------------------------------------
__global__ __launch_bounds__(256) void stats1_kernel(
    const unsigned short* __restrict__ ub,
    float* __restrict__ sums, float* __restrict__ sumsq)
{
  int row = blockIdx.x, tid = threadIdx.x;
  const unsigned int* zr = (const unsigned int*)ub + (size_t)row * 16384;
  float s1 = 0.0f, s2 = 0.0f;
  #pragma unroll
  for (int rd = 0; rd < 8; rd++) {
    uint4 v = *reinterpret_cast<const uint4*>(zr + rd * 1024 + tid * 4);
    unsigned int ws_[4] = {v.x, v.y, v.z, v.w};
    #pragma unroll
    for (int k = 0; k < 4; k++) {
      float f0 = bf2f(ws_[k] & 0xFFFFu), f1 = bf2f(ws_[k] >> 16);
      s1 += f0 + f1;
      s2 = fmaf(f0, f0, fmaf(f1, f1, s2));
    }
  }
  #pragma unroll
  for (int off = 1; off < 64; off <<= 1) {
    s1 += __shfl_xor(s1, off);
    s2 += __shfl_xor(s2, off);
  }
  __shared__ float a1[4], a2[4];
  int wv = tid >> 6;
  if ((tid & 63) == 0) { a1[wv] = s1; a2[wv] = s2; }
  __syncthreads();
  if (tid == 0) {
    sums[row]  = a1[0] + a1[1] + a1[2] + a1[3];
    sumsq[row] = a2[0] + a2[1] + a2[2] + a2[3];
  }
}

__global__ void stats2_kernel(const float* __restrict__ sums,
                              const float* __restrict__ sumsq,
                              float* __restrict__ meanp, float* __restrict__ invp)
{
  int g = threadIdx.x;
  if (g < H_) {
    double s1 = 0.0, s2 = 0.0;
    #pragma unroll
    for (int b = 0; b < B_; b++) {
      s1 += (double)sums[b * H_ + g];
      s2 += (double)sumsq[b * H_ + g];
    }
    double cnt = (double)B_ * (double)L_;
    double mu  = s1 / cnt;
    double var = s2 / cnt - mu * mu;
    meanp[g] = (float)mu;
    invp[g]  = (float)(1.0 / sqrt(var + 1e-5));
  }
}

// ---------------------------------------------------------------------------
// final2: one block per row; z bf16 -> regs, barrier, BN+FiLM+prelu+residual,
// write f32 over the same row slot (in-place safe via the barrier).
// ---------------------------------------------------------------------------
__global__ __launch_bounds__(256) void final2_kernel(
    unsigned short* __restrict__ ub, float* __restrict__ outf,
    const float* __restrict__ x,
    const float* __restrict__ meanp, const float* __restrict__ invp,
    const float* __restrict__ gact, const float* __restrict__ bact,
    const float* __restrict__ prelu2_a, const float* __restrict__ res_w)
{
  int row = blockIdx.x, tid = threadIdx.x;
  int b = row >> 7, g = row & 127;
  const unsigned int* zr = (const unsigned int*)ub + (size_t)row * 16384;
  uint4 zq0 = *reinterpret_cast<const uint4*>(zr + 0 * 1024 + tid * 4);
  uint4 zq1 = *reinterpret_cast<const uint4*>(zr + 1 * 1024 + tid * 4);
  uint4 zq2 = *reinterpret_cast<const uint4*>(zr + 2 * 1024 + tid * 4);
  uint4 zq3 = *reinterpret_cast<const uint4*>(zr + 3 * 1024 + tid * 4);
  uint4 zq4 = *reinterpret_cast<const uint4*>(zr + 4 * 1024 + tid * 4);
  uint4 zq5 = *reinterpret_cast<const uint4*>(zr + 5 * 1024 + tid * 4);
  uint4 zq6 = *reinterpret_cast<const uint4*>(zr + 6 * 1024 + tid * 4);
  uint4 zq7 = *reinterpret_cast<const uint4*>(zr + 7 * 1024 + tid * 4);
  __syncthreads();   // all z reads complete before any f32 write to the slot

  float m  = meanp[g], iv = invp[g];
  float ga = gact[b * H_ + g], bb = bact[b * H_ + g];
  float rw = res_w[g], pa = prelu2_a[0];
  const float* xr = x + (size_t)row * L_;
  float* orow = outf + (size_t)row * L_;

  uint4 zqa[8] = {zq0, zq1, zq2, zq3, zq4, zq5, zq6, zq7};
  #pragma unroll
  for (int rd = 0; rd < 8; rd++) {
    int e0 = rd * 2048 + tid * 8;
    f32x4 x0 = *reinterpret_cast<const f32x4*>(xr + e0);
    f32x4 x1 = *reinterpret_cast<const f32x4*>(xr + e0 + 4);
    unsigned int wz[4] = {zqa[rd].x, zqa[rd].y, zqa[rd].z, zqa[rd].w};
    f32x4 o0, o1;
    #pragma unroll
    for (int k = 0; k < 4; k++) {
      float z0 = bf2f(wz[k] & 0xFFFFu), z1 = bf2f(wz[k] >> 16);
      float v0 = fmaf((z0 - m) * iv, ga, bb);
      float v1 = fmaf((z1 - m) * iv, ga, bb);
      v0 = (v0 > 0.0f) ? v0 : pa * v0;
      v1 = (v1 > 0.0f) ? v1 : pa * v1;
      float xa = (k < 2) ? x0[2 * k] : x1[2 * k - 4];
      float xbv = (k < 2) ? x0[2 * k + 1] : x1[2 * k - 3];
      float r0 = fmaf(rw, xa, v0);
      float r1 = fmaf(rw, xbv, v1);
      if (k < 2) { o0[2 * k] = r0; o0[2 * k + 1] = r1; }
      else       { o1[2 * k - 4] = r0; o1[2 * k - 3] = r1; }
    }
    *reinterpret_cast<f32x4*>(orow + e0)     = o0;
    *reinterpret_cast<f32x4*>(orow + e0 + 4) = o1;
  }
}

// ---------------------------------------------------------------------------
extern "C" void kernel_launch(void* const* d_in, const int* in_sizes, int n_in,
                              void* d_out, int out_size, void* d_ws, size_t ws_size,
                              hipStream_t stream)
{
  const float* x        = (const float*)d_in[0];
  const float* cond     = (const float*)d_in[1];
  const float* lin_w    = (const float*)d_in[2];
  const float* lin_b    = (const float*)d_in[3];
  const float* prelu1_a = (const float*)d_in[4];
  const float* log_dt   = (const float*)d_in[5];
  const float* log_A    = (const float*)d_in[6];
  const float* A_imag   = (const float*)d_in[7];
  const float* C_re     = (const float*)d_in[8];
  const float* C_im     = (const float*)d_in[9];
  const float* Dp       = (const float*)d_in[10];
  const float* out_w    = (const float*)d_in[11];
  const float* out_b    = (const float*)d_in[12];
  const float* film_w   = (const float*)d_in[13];
  const float* film_b   = (const float*)d_in[14];
  const float* prelu2_a = (const float*)d_in[15];
  const float* res_w    = (const float*)d_in[16];
  float* outf = (float*)d_out;
  unsigned short* ubuf = (unsigned short*)d_out;

  char* wsb = (char*)d_ws;               // ~129 KB total
  float* consts         = (float*)(wsb + 0);        // 12288 f32 = 48 KB
  unsigned short* wA16  = (unsigned short*)(wsb + 49152);   // 32 KB
  unsigned short* wB16  = (unsigned short*)(wsb + 81920);   // 32 KB
  float* gact           = (float*)(wsb + 114688);   // 4 KB
  float* bact           = (float*)(wsb + 118784);   // 4 KB
  float* meanp          = (float*)(wsb + 122880);   // 512 B
  float* invp           = (float*)(wsb + 123392);   // 512 B
  float* sums           = (float*)(wsb + 123904);   // 4 KB
  float* sumsq          = (float*)(wsb + 128000);   // 4 KB

  prep2_kernel<<<18, 256, 0, stream>>>(lin_w, out_w, log_dt, log_A, A_imag, C_re, C_im,
                                       cond, film_w, film_b, wA16, wB16, consts, gact, bact);
  // lin + prelu: x (f32) -> u (bf16 row slots in d_out)
  mgemm_kernel<0><<<2048, 256, 0, stream>>>(x, wA16, lin_b, prelu1_a, ubuf);
  // SSM scan: u -> y, bf16, in place per row
  scan3_kernel<<<1024, 1024, 0, stream>>>(ubuf, consts, Dp);
  // out layer + bias: y (bf16) -> z (bf16), in place
  mgemm_kernel<1><<<2048, 256, 0, stream>>>(ubuf, wB16, out_b, nullptr, ubuf);
  // BN stats over z
  stats1_kernel<<<1024, 256, 0, stream>>>(ubuf, sums, sumsq);
  stats2_kernel<<<1, 128, 0, stream>>>(sums, sumsq, meanp, invp);
  // BN + FiLM + prelu2 + residual: z (bf16) -> out (f32), in place per row
  final2_kernel<<<1024, 256, 0, stream>>>(ubuf, outf, x, meanp, invp, gact, bact,
                                          prelu2_a, res_w);
}

// Round 8
// 314.626 us; speedup vs baseline: 2.8511x; 1.0546x over previous
//
#include <hip/hip_runtime.h>
#include <math.h>

#define B_ 8
#define H_ 128
#define L_ 16384
#define N_ 16
#define CHUNK_ 64
#define NCH_ 256   // L_ / CHUNK_

typedef float f32x4 __attribute__((ext_vector_type(4)));
typedef short bf16x8 __attribute__((ext_vector_type(8)));

static __device__ __forceinline__ unsigned int f2bf(float f) {
  unsigned int u = __float_as_uint(f);
  return (u + 0x7FFFu + ((u >> 16) & 1u)) >> 16;   // RNE bf16
}
static __device__ __forceinline__ float bf2f(unsigned int us) {
  return __uint_as_float(us << 16);
}

// ---------------------------------------------------------------------------
// prep2: parallel weight bf16 conversion + SSM constants + FiLM
// ---------------------------------------------------------------------------
__global__ __launch_bounds__(256) void prep2_kernel(
    const float* __restrict__ lin_w, const float* __restrict__ out_w,
    const float* __restrict__ log_dt, const float* __restrict__ log_A_real,
    const float* __restrict__ A_imag, const float* __restrict__ C_re,
    const float* __restrict__ C_im, const float* __restrict__ cond,
    const float* __restrict__ film_w, const float* __restrict__ film_b,
    unsigned short* __restrict__ wA16, unsigned short* __restrict__ wB16,
    float* __restrict__ consts,
    float* __restrict__ gact, float* __restrict__ bact)
{
  int blk = blockIdx.x, t = threadIdx.x;
  if (blk < 16) {
    int base = blk * 1024;
    #pragma unroll
    for (int it = 0; it < 4; it++) {
      int i = base + it * 256 + t;
      wA16[i] = (unsigned short)f2bf(lin_w[i]);
      wB16[i] = (unsigned short)f2bf(out_w[i]);
    }
  } else if (blk == 16) {
    for (int i = t; i < H_ * N_; i += 256) {
      int h = i >> 4, n = i & 15;
      float dt  = expf(log_dt[h]);
      float Are = -expf(log_A_real[i]);
      float Aim = A_imag[i];
      float dre = dt * Are, dim = dt * Aim;
      float er  = expf(dre);
      float wre = er * cosf(dim);
      float wim = er * sinf(dim);
      float den = Are * Are + Aim * Aim;
      float nre = wre - 1.0f, nim = wim;
      float dBre = (nre * Are + nim * Aim) / den;
      float dBim = (nim * Are - nre * Aim) / den;
      float cr = C_re[i], ci = C_im[i];
      float cere = cr * dBre - ci * dBim;
      float ceim = cr * dBim + ci * dBre;
      float e2   = expf((float)CHUNK_ * dre);
      float wcre = e2 * cosf((float)CHUNK_ * dim);
      float wcim = e2 * sinf((float)CHUNK_ * dim);
      float* cb = consts + h * 96;
      cb[n]      = wre;  cb[16 + n] = wim;
      cb[32 + n] = cere; cb[48 + n] = ceim;
      cb[64 + n] = wcre; cb[80 + n] = wcim;
    }
  } else {
    for (int i = t; i < B_ * 2 * H_; i += 256) {
      int b = i >> 8, k = i & 255;
      float acc = film_b[k];
      #pragma unroll
      for (int c = 0; c < 4; c++) acc += cond[b * 4 + c] * film_w[k * 4 + c];
      if (k < H_) gact[b * H_ + k] = acc;
      else        bact[b * H_ + (k - H_)] = acc;
    }
  }
}

// ---------------------------------------------------------------------------
// MFMA GEMM, 128g x 128j tile, K=128.  MODE 0: x f32 -> u bf16 (+prelu).
// MODE 1: y bf16 -> z bf16 (+bias).  bf16 intermediates in the first 32KB of
// each row's 64KB f32 slot in d_out.  Col-disjoint across blocks -> in-place
// safe (block reads all h rows of cols [jb,jb+128) before any store).
// ---------------------------------------------------------------------------
template<int MODE>
__global__ __launch_bounds__(256) void mgemm_kernel(
    const void* inv, const unsigned short* __restrict__ w16,
    const float* __restrict__ bias, const float* __restrict__ prelu_a,
    unsigned short* __restrict__ outb)
{
  __shared__ __align__(16) unsigned short xT[128 * 128];  // 32KB swizzled [j][h]
  char* xb = (char*)xT;
  int tid = threadIdx.x;
  int blk = blockIdx.x;
  int b   = blk >> 7;
  int jb  = (blk & 127) << 7;

  // ---- stage x^T tile (128j x 128h) as bf16, XOR-swizzled ----
  {
    int hp = tid >> 4;        // h-group: h0 = hp*8
    int jq = tid & 15;        // j-group: j0 = jq*8
    int h0 = hp << 3;
    int j0 = jq << 3;
    if (MODE == 0) {
      const float* inb = (const float*)inv + ((size_t)b * H_) * L_ + jb;
      f32x4 r[8][2];
      #pragma unroll
      for (int rr = 0; rr < 8; rr++) {
        r[rr][0] = *reinterpret_cast<const f32x4*>(&inb[(size_t)(h0 + rr) * L_ + j0]);
        r[rr][1] = *reinterpret_cast<const f32x4*>(&inb[(size_t)(h0 + rr) * L_ + j0 + 4]);
      }
      #pragma unroll
      for (int jj = 0; jj < 8; jj++) {
        int j = j0 + jj;
        uint4 pk;
        #define GE_(rr) ((jj < 4) ? r[rr][0][jj] : r[rr][1][jj - 4])
        pk.x = f2bf(GE_(0)) | (f2bf(GE_(1)) << 16);
        pk.y = f2bf(GE_(2)) | (f2bf(GE_(3)) << 16);
        pk.z = f2bf(GE_(4)) | (f2bf(GE_(5)) << 16);
        pk.w = f2bf(GE_(6)) | (f2bf(GE_(7)) << 16);
        #undef GE_
        int addr = j * 256 + ((hp << 4) ^ ((j & 15) << 4));
        *reinterpret_cast<uint4*>(xb + addr) = pk;
      }
    } else {
      const unsigned short* ub = (const unsigned short*)inv;
      uint4 rv[8];
      #pragma unroll
      for (int rr = 0; rr < 8; rr++)
        rv[rr] = *reinterpret_cast<const uint4*>(
            ub + ((size_t)(b * H_ + h0 + rr)) * 32768 + jb + j0);
      #pragma unroll
      for (int jj = 0; jj < 8; jj++) {
        int j = j0 + jj;
        uint4 pk;
        #define WD_(rr) ((jj >> 1) == 0 ? rv[rr].x : (jj >> 1) == 1 ? rv[rr].y : \
                         (jj >> 1) == 2 ? rv[rr].z : rv[rr].w)
        #define EXT_(rr) (((jj & 1) ? (WD_(rr) >> 16) : WD_(rr)) & 0xFFFFu)
        pk.x = EXT_(0) | (EXT_(1) << 16);
        pk.y = EXT_(2) | (EXT_(3) << 16);
        pk.z = EXT_(4) | (EXT_(5) << 16);
        pk.w = EXT_(6) | (EXT_(7) << 16);
        #undef EXT_
        #undef WD_
        int addr = j * 256 + ((hp << 4) ^ ((j & 15) << 4));
        *reinterpret_cast<uint4*>(xb + addr) = pk;
      }
    }
  }
  __syncthreads();

  // ---- MFMA compute: wave tile 64g x 64j ----
  int lane = tid & 63;
  int w    = tid >> 6;
  int wg   = w >> 1;
  int wj   = w & 1;
  int ln   = lane & 15;
  int q    = lane >> 4;
  f32x4 acc[4][4];
  #pragma unroll
  for (int mi = 0; mi < 4; mi++)
    #pragma unroll
    for (int n = 0; n < 4; n++) acc[mi][n] = (f32x4)0.0f;

  #pragma unroll
  for (int kb = 0; kb < 4; kb++) {
    bf16x8 a[4], bv[4];
    #pragma unroll
    for (int mi = 0; mi < 4; mi++)
      a[mi] = *reinterpret_cast<const bf16x8*>(
          &w16[(size_t)(wg * 64 + mi * 16 + ln) * 128 + kb * 32 + q * 8]);
    #pragma unroll
    for (int n = 0; n < 4; n++) {
      int jl = wj * 64 + n * 16 + ln;
      int ar = jl * 256 + (((kb << 6) + (q << 4)) ^ ((jl & 15) << 4));
      bv[n] = *reinterpret_cast<bf16x8*>(xb + ar);
    }
    #pragma unroll
    for (int mi = 0; mi < 4; mi++)
      #pragma unroll
      for (int n = 0; n < 4; n++)
        acc[mi][n] = __builtin_amdgcn_mfma_f32_16x16x32_bf16(a[mi], bv[n], acc[mi][n], 0, 0, 0);
  }

  // ---- epilogue: bf16 stores into row slots ----
  float pa = (MODE == 0) ? prelu_a[0] : 0.0f;
  #pragma unroll
  for (int mi = 0; mi < 4; mi++) {
    #pragma unroll
    for (int r = 0; r < 4; r++) {
      int g = wg * 64 + mi * 16 + q * 4 + r;
      float bvs = bias[g];
      size_t orow = ((size_t)(b * H_ + g)) * 32768 + jb + wj * 64 + ln;
      #pragma unroll
      for (int n = 0; n < 4; n++) {
        float v = acc[mi][n][r] + bvs;
        if (MODE == 0) v = (v > 0.0f) ? v : pa * v;
        outb[orow + n * 16] = (unsigned short)f2bf(v);
      }
    }
  }
}

// ---------------------------------------------------------------------------
// scan4: chunked SSM scan, bf16 row in LDS, 4-way mode split.
// 1024 thr: thread = (chunk c = tid>>2, mode-group m = tid&3).
// Cross-chunk combine: in-wave shfl_up Kogge-Stone (4 steps, 0 barriers) +
// one LDS publish of 16 wave aggregates + per-thread redundant fold.
// 3 barriers total (vs 19 in scan3).  b64 LDS reads, 4 elems/iter.
// Swizzle: idx ^ ((chunk&7)<<2)  (quad-granular, intra-chunk, b64-safe).
// ---------------------------------------------------------------------------
__global__ __launch_bounds__(1024) void scan4_kernel(
    unsigned short* ub, const float* __restrict__ consts, const float* __restrict__ Dp)
{
  __shared__ unsigned int rowl[8192];      // 16384 bf16, swizzled
  __shared__ float agg[16][32];            // wave aggregates [wave][m*8+2k(+1)]
  int tid = threadIdx.x;
  int row = blockIdx.x;
  int h   = row & 127;
  const float* cb = consts + h * 96;
  unsigned int* grow = (unsigned int*)ub + (size_t)row * 16384;

  // ---- stage in ----
  #pragma unroll
  for (int rd = 0; rd < 2; rd++) {
    int u0   = rd * 4096 + tid * 4;
    uint4 v  = *reinterpret_cast<const uint4*>(grow + u0);
    int phys = u0 ^ (((u0 >> 5) & 7) << 2);
    *reinterpret_cast<uint4*>(&rowl[phys]) = v;
  }
  __syncthreads();

  int c     = tid >> 2;          // chunk 0..255
  int m     = tid & 3;           // mode group (modes 4m..4m+3)
  int lane  = tid & 63;
  int cl    = lane >> 2;         // chunk-local within wave, 0..15
  int wv    = tid >> 6;          // wave id 0..15
  int cbase = c * 32;
  int swz   = (c & 7) << 2;

  float wre[4], wim[4];
  #pragma unroll
  for (int k = 0; k < 4; k++) { wre[k] = cb[4*m+k]; wim[k] = cb[16+4*m+k]; }

  float sre[4] = {0.f,0.f,0.f,0.f}, sim[4] = {0.f,0.f,0.f,0.f};

  #define UPD_(uval) { \
    _Pragma("unroll") \
    for (int k = 0; k < 4; k++) { \
      float nr = fmaf(wre[k], sre[k], fmaf(-wim[k], sim[k], (uval))); \
      float ni = fmaf(wre[k], sim[k], wim[k] * sre[k]); \
      sre[k] = nr; sim[k] = ni; } }

  // ---- phase 1: local chunk states (4 elems / iter) ----
  for (int e2 = 0; e2 < 16; e2++) {
    int idx  = (cbase + 2 * e2) ^ swz;
    uint2 pv = *reinterpret_cast<uint2*>(&rowl[idx]);
    float u0 = __uint_as_float(pv.x << 16);
    float u1 = __uint_as_float(pv.x & 0xFFFF0000u);
    float u2 = __uint_as_float(pv.y << 16);
    float u3 = __uint_as_float(pv.y & 0xFFFF0000u);
    UPD_(u0); UPD_(u1); UPD_(u2); UPD_(u3);
  }

  // ---- in-wave Kogge-Stone over 16 chunks via shfl_up; also accumulate
  //      pw = wc^cl for the phase-2 seed ----
  float mre[4], mim[4];
  #pragma unroll
  for (int k = 0; k < 4; k++) { mre[k] = cb[64+4*m+k]; mim[k] = cb[80+4*m+k]; }
  float pwr[4] = {1.f,1.f,1.f,1.f}, pwi[4] = {0.f,0.f,0.f,0.f};
  #pragma unroll
  for (int s = 0; s < 4; s++) {
    int off = 1 << s;
    bool bit = (cl >> s) & 1;
    #pragma unroll
    for (int k = 0; k < 4; k++) {          // pw *= wc^(2^s) if bit
      float tr = fmaf(pwr[k], mre[k], -(pwi[k] * mim[k]));
      float ti = fmaf(pwr[k], mim[k],  (pwi[k] * mre[k]));
      pwr[k] = bit ? tr : pwr[k];
      pwi[k] = bit ? ti : pwi[k];
    }
    bool act = (cl >= off);
    #pragma unroll
    for (int k = 0; k < 4; k++) {
      float pr = __shfl_up(sre[k], 4 * off, 64);
      float pi = __shfl_up(sim[k], 4 * off, 64);
      float nr = fmaf(mre[k], pr, fmaf(-mim[k], pi, sre[k]));
      float ni = fmaf(mre[k], pi, fmaf( mim[k], pr, sim[k]));
      sre[k] = act ? nr : sre[k];
      sim[k] = act ? ni : sim[k];
    }
    #pragma unroll
    for (int k = 0; k < 4; k++) {          // square multiplier
      float r = mre[k], i2 = mim[k];
      mre[k] = fmaf(r, r, -(i2 * i2));
      mim[k] = 2.0f * r * i2;
    }
  }
  // mre/mim now hold wc^16 (one wave span)

  // ---- publish wave aggregates, fold preceding waves ----
  if (cl == 15) {
    #pragma unroll
    for (int k = 0; k < 4; k++) {
      agg[wv][m * 8 + 2 * k]     = sre[k];
      agg[wv][m * 8 + 2 * k + 1] = sim[k];
    }
  }
  __syncthreads();
  float Cr[4] = {0.f,0.f,0.f,0.f}, Ci[4] = {0.f,0.f,0.f,0.f};
  for (int wp = 0; wp < wv; wp++) {        // wave-uniform trip count
    #pragma unroll
    for (int k = 0; k < 4; k++) {
      float ar = agg[wp][m * 8 + 2 * k];
      float ai = agg[wp][m * 8 + 2 * k + 1];
      float nr = fmaf(mre[k], Cr[k], fmaf(-mim[k], Ci[k], ar));
      float ni = fmaf(mre[k], Ci[k], fmaf( mim[k], Cr[k], ai));
      Cr[k] = nr; Ci[k] = ni;
    }
  }

  // ---- phase-2 seed: I_{c-1} = I_loc_{c-1} + wc^cl * C ----
  #pragma unroll
  for (int k = 0; k < 4; k++) {
    float er = __shfl_up(sre[k], 4, 64);
    float ei = __shfl_up(sim[k], 4, 64);
    float br = (cl == 0) ? 0.0f : er;
    float bi = (cl == 0) ? 0.0f : ei;
    sre[k] = fmaf(pwr[k], Cr[k], fmaf(-pwi[k], Ci[k], br));
    sim[k] = fmaf(pwr[k], Ci[k], fmaf( pwi[k], Cr[k], bi));
  }

  // ---- phase 2: seeded re-scan, emit y ----
  float cre[4], cim[4];
  #pragma unroll
  for (int k = 0; k < 4; k++) { cre[k] = cb[32+4*m+k]; cim[k] = cb[48+4*m+k]; }
  float Dv = Dp[h];

  #define STEP_(uval, yout) { \
    float ya = 0.0f; \
    _Pragma("unroll") \
    for (int k = 0; k < 4; k++) { \
      float nr = fmaf(wre[k], sre[k], fmaf(-wim[k], sim[k], (uval))); \
      float ni = fmaf(wre[k], sim[k], wim[k] * sre[k]); \
      sre[k] = nr; sim[k] = ni; \
      ya = fmaf(cre[k], nr, fmaf(-cim[k], ni, ya)); } \
    yout = ya; }

  for (int e2 = 0; e2 < 16; e2++) {
    int idx  = (cbase + 2 * e2) ^ swz;
    uint2 pv = *reinterpret_cast<uint2*>(&rowl[idx]);
    float u0 = __uint_as_float(pv.x << 16);
    float u1 = __uint_as_float(pv.x & 0xFFFF0000u);
    float u2 = __uint_as_float(pv.y << 16);
    float u3 = __uint_as_float(pv.y & 0xFFFF0000u);
    float y0, y1, y2, y3;
    STEP_(u0, y0); STEP_(u1, y1); STEP_(u2, y2); STEP_(u3, y3);
    y0 += __shfl_xor(y0, 1); y0 += __shfl_xor(y0, 2);
    y1 += __shfl_xor(y1, 1); y1 += __shfl_xor(y1, 2);
    y2 += __shfl_xor(y2, 1); y2 += __shfl_xor(y2, 2);
    y3 += __shfl_xor(y3, 1); y3 += __shfl_xor(y3, 2);
    if (m == 0) {
      y0 = fmaf(Dv, u0, 2.0f * y0);
      y1 = fmaf(Dv, u1, 2.0f * y1);
      y2 = fmaf(Dv, u2, 2.0f * y2);
      y3 = fmaf(Dv, u3, 2.0f * y3);
      uint2 pk;
      pk.x = f2bf(y0) | (f2bf(y1) << 16);
      pk.y = f2bf(y2) | (f2bf(y3) << 16);
      *reinterpret_cast<uint2*>(&rowl[idx]) = pk;
    }
  }
  #undef UPD_
  #undef STEP_
  __syncthreads();

  // ---- stage out ----
  #pragma unroll
  for (int rd = 0; rd < 2; rd++) {
    int u0   = rd * 4096 + tid * 4;
    int phys = u0 ^ (((u0 >> 5) & 7) << 2);
    uint4 v  = *reinterpret_cast<const uint4*>(&rowl[phys]);
    *reinterpret_cast<uint4*>(grow + u0) = v;
  }
}

// ---------------------------------------------------------------------------
// stats1: per-row (b,g) sums of z (bf16) -> ws partials
// ---------------------------------------------------------------------------
__global__ __launch_bounds__(256) void stats1_kernel(
    const unsigned short* __restrict__ ub,
    float* __restrict__ sums, float* __restrict__ sumsq)
{
  int row = blockIdx.x, tid = threadIdx.x;
  const unsigned int* zr = (const unsigned int*)ub + (size_t)row * 16384;
  float s1 = 0.0f, s2 = 0.0f;
  #pragma unroll
  for (int rd = 0; rd < 8; rd++) {
    uint4 v = *reinterpret_cast<const uint4*>(zr + rd * 1024 + tid * 4);
    unsigned int ws_[4] = {v.x, v.y, v.z, v.w};
    #pragma unroll
    for (int k = 0; k < 4; k++) {
      float f0 = bf2f(ws_[k] & 0xFFFFu), f1 = bf2f(ws_[k] >> 16);
      s1 += f0 + f1;
      s2 = fmaf(f0, f0, fmaf(f1, f1, s2));
    }
  }
  #pragma unroll
  for (int off = 1; off < 64; off <<= 1) {
    s1 += __shfl_xor(s1, off);
    s2 += __shfl_xor(s2, off);
  }
  __shared__ float a1[4], a2[4];
  int wv = tid >> 6;
  if ((tid & 63) == 0) { a1[wv] = s1; a2[wv] = s2; }
  __syncthreads();
  if (tid == 0) {
    sums[row]  = a1[0] + a1[1] + a1[2] + a1[3];
    sumsq[row] = a2[0] + a2[1] + a2[2] + a2[3];
  }
}

__global__ void stats2_kernel(const float* __restrict__ sums,
                              const float* __restrict__ sumsq,
                              float* __restrict__ meanp, float* __restrict__ invp)
{
  int g = threadIdx.x;
  if (g < H_) {
    double s1 = 0.0, s2 = 0.0;
    #pragma unroll
    for (int b = 0; b < B_; b++) {
      s1 += (double)sums[b * H_ + g];
      s2 += (double)sumsq[b * H_ + g];
    }
    double cnt = (double)B_ * (double)L_;
    double mu  = s1 / cnt;
    double var = s2 / cnt - mu * mu;
    meanp[g] = (float)mu;
    invp[g]  = (float)(1.0 / sqrt(var + 1e-5));
  }
}

// ---------------------------------------------------------------------------
// final2: one block per row; z bf16 -> regs, barrier, BN+FiLM+prelu+residual,
// write f32 over the same row slot (in-place safe via the barrier).
// ---------------------------------------------------------------------------
__global__ __launch_bounds__(256) void final2_kernel(
    unsigned short* __restrict__ ub, float* __restrict__ outf,
    const float* __restrict__ x,
    const float* __restrict__ meanp, const float* __restrict__ invp,
    const float* __restrict__ gact, const float* __restrict__ bact,
    const float* __restrict__ prelu2_a, const float* __restrict__ res_w)
{
  int row = blockIdx.x, tid = threadIdx.x;
  int b = row >> 7, g = row & 127;
  const unsigned int* zr = (const unsigned int*)ub + (size_t)row * 16384;
  uint4 zq0 = *reinterpret_cast<const uint4*>(zr + 0 * 1024 + tid * 4);
  uint4 zq1 = *reinterpret_cast<const uint4*>(zr + 1 * 1024 + tid * 4);
  uint4 zq2 = *reinterpret_cast<const uint4*>(zr + 2 * 1024 + tid * 4);
  uint4 zq3 = *reinterpret_cast<const uint4*>(zr + 3 * 1024 + tid * 4);
  uint4 zq4 = *reinterpret_cast<const uint4*>(zr + 4 * 1024 + tid * 4);
  uint4 zq5 = *reinterpret_cast<const uint4*>(zr + 5 * 1024 + tid * 4);
  uint4 zq6 = *reinterpret_cast<const uint4*>(zr + 6 * 1024 + tid * 4);
  uint4 zq7 = *reinterpret_cast<const uint4*>(zr + 7 * 1024 + tid * 4);
  __syncthreads();   // all z reads complete before any f32 write to the slot

  float m  = meanp[g], iv = invp[g];
  float ga = gact[b * H_ + g], bb = bact[b * H_ + g];
  float rw = res_w[g], pa = prelu2_a[0];
  const float* xr = x + (size_t)row * L_;
  float* orow = outf + (size_t)row * L_;

  uint4 zqa[8] = {zq0, zq1, zq2, zq3, zq4, zq5, zq6, zq7};
  #pragma unroll
  for (int rd = 0; rd < 8; rd++) {
    int e0 = rd * 2048 + tid * 8;
    f32x4 x0 = *reinterpret_cast<const f32x4*>(xr + e0);
    f32x4 x1 = *reinterpret_cast<const f32x4*>(xr + e0 + 4);
    unsigned int wz[4] = {zqa[rd].x, zqa[rd].y, zqa[rd].z, zqa[rd].w};
    f32x4 o0, o1;
    #pragma unroll
    for (int k = 0; k < 4; k++) {
      float z0 = bf2f(wz[k] & 0xFFFFu), z1 = bf2f(wz[k] >> 16);
      float v0 = fmaf((z0 - m) * iv, ga, bb);
      float v1 = fmaf((z1 - m) * iv, ga, bb);
      v0 = (v0 > 0.0f) ? v0 : pa * v0;
      v1 = (v1 > 0.0f) ? v1 : pa * v1;
      float xa = (k < 2) ? x0[2 * k] : x1[2 * k - 4];
      float xbv = (k < 2) ? x0[2 * k + 1] : x1[2 * k - 3];
      float r0 = fmaf(rw, xa, v0);
      float r1 = fmaf(rw, xbv, v1);
      if (k < 2) { o0[2 * k] = r0; o0[2 * k + 1] = r1; }
      else       { o1[2 * k - 4] = r0; o1[2 * k - 3] = r1; }
    }
    *reinterpret_cast<f32x4*>(orow + e0)     = o0;
    *reinterpret_cast<f32x4*>(orow + e0 + 4) = o1;
  }
}

// ---------------------------------------------------------------------------
extern "C" void kernel_launch(void* const* d_in, const int* in_sizes, int n_in,
                              void* d_out, int out_size, void* d_ws, size_t ws_size,
                              hipStream_t stream)
{
  const float* x        = (const float*)d_in[0];
  const float* cond     = (const float*)d_in[1];
  const float* lin_w    = (const float*)d_in[2];
  const float* lin_b    = (const float*)d_in[3];
  const float* prelu1_a = (const float*)d_in[4];
  const float* log_dt   = (const float*)d_in[5];
  const float* log_A    = (const float*)d_in[6];
  const float* A_imag   = (const float*)d_in[7];
  const float* C_re     = (const float*)d_in[8];
  const float* C_im     = (const float*)d_in[9];
  const float* Dp       = (const float*)d_in[10];
  const float* out_w    = (const float*)d_in[11];
  const float* out_b    = (const float*)d_in[12];
  const float* film_w   = (const float*)d_in[13];
  const float* film_b   = (const float*)d_in[14];
  const float* prelu2_a = (const float*)d_in[15];
  const float* res_w    = (const float*)d_in[16];
  float* outf = (float*)d_out;
  unsigned short* ubuf = (unsigned short*)d_out;

  char* wsb = (char*)d_ws;               // ~129 KB total
  float* consts         = (float*)(wsb + 0);        // 12288 f32 = 48 KB
  unsigned short* wA16  = (unsigned short*)(wsb + 49152);   // 32 KB
  unsigned short* wB16  = (unsigned short*)(wsb + 81920);   // 32 KB
  float* gact           = (float*)(wsb + 114688);   // 4 KB
  float* bact           = (float*)(wsb + 118784);   // 4 KB
  float* meanp          = (float*)(wsb + 122880);   // 512 B
  float* invp           = (float*)(wsb + 123392);   // 512 B
  float* sums           = (float*)(wsb + 123904);   // 4 KB
  float* sumsq          = (float*)(wsb + 128000);   // 4 KB

  prep2_kernel<<<18, 256, 0, stream>>>(lin_w, out_w, log_dt, log_A, A_imag, C_re, C_im,
                                       cond, film_w, film_b, wA16, wB16, consts, gact, bact);
  // lin + prelu: x (f32) -> u (bf16 row slots in d_out)
  mgemm_kernel<0><<<1024, 256, 0, stream>>>(x, wA16, lin_b, prelu1_a, ubuf);
  // SSM scan: u -> y, bf16, in place per row
  scan4_kernel<<<1024, 1024, 0, stream>>>(ubuf, consts, Dp);
  // out layer + bias: y (bf16) -> z (bf16), in place
  mgemm_kernel<1><<<1024, 256, 0, stream>>>(ubuf, wB16, out_b, nullptr, ubuf);
  // BN stats over z
  stats1_kernel<<<1024, 256, 0, stream>>>(ubuf, sums, sumsq);
  stats2_kernel<<<1, 128, 0, stream>>>(sums, sumsq, meanp, invp);
  // BN + FiLM + prelu2 + residual: z (bf16) -> out (f32), in place per row
  final2_kernel<<<1024, 256, 0, stream>>>(ubuf, outf, x, meanp, invp, gact, bact,
                                          prelu2_a, res_w);
}